// Round 1
// baseline (425.016 us; speedup 1.0000x reference)
//
#include <hip/hip_runtime.h>
#include <hip/hip_bf16.h>

#define B_ 4
#define N_ 2048
#define M_ 2048
#define D_ 128
#define QBLK 64
#define KVBLK 64

typedef __attribute__((ext_vector_type(8))) short short8;
typedef __attribute__((ext_vector_type(4))) float floatx4;
typedef unsigned short u16;
typedef unsigned int u32;

__device__ __forceinline__ u16 f2bf(float x) {
  u32 u = __builtin_bit_cast(u32, x);
  u32 r = (u + 0x7FFFu + ((u >> 16) & 1u)) >> 16;
  return (u16)r;
}
__device__ __forceinline__ float bf2f(u16 h) {
  u32 u = ((u32)h) << 16;
  return __builtin_bit_cast(float, u);
}

__global__ __launch_bounds__(256) void rbf_attn_kernel(
    const float* __restrict__ q, const float* __restrict__ k,
    const float* __restrict__ v, float* __restrict__ out)
{
  __shared__ u16 Khi[KVBLK][136];
  __shared__ u16 Klo[KVBLK][136];
  __shared__ u16 Vt[D_][72];
  __shared__ u16 Plds[4][16][72];
  __shared__ float k2s[KVBLK];

  const int tid = threadIdx.x;
  const int w = tid >> 6;
  const int lane = tid & 63;
  const int l15 = lane & 15;
  const int l16 = lane >> 4;

  const int b = blockIdx.y;
  const int q0 = blockIdx.x * QBLK;

  const float* qb = q + (size_t)b * N_ * D_;
  const float* kb = k + (size_t)b * M_ * D_;
  const float* vb = v + (size_t)b * M_ * D_;
  float* ob = out + (size_t)b * N_ * D_;

  // ---- Load Q fragments (hi/lo bf16 split). Wave's rows: q0 + w*16 + l15
  short8 qh[4], ql[4];
  {
    const float* qp = qb + (size_t)(q0 + w * 16 + l15) * D_ + l16 * 8;
    #pragma unroll
    for (int t = 0; t < 4; ++t) {
      float4 a = *(const float4*)(qp + t * 32);
      float4 c = *(const float4*)(qp + t * 32 + 4);
      float xs[8] = {a.x, a.y, a.z, a.w, c.x, c.y, c.z, c.w};
      #pragma unroll
      for (int j = 0; j < 8; ++j) {
        u16 h = f2bf(xs[j]);
        float rem = xs[j] - bf2f(h);
        qh[t][j] = (short)h;
        ql[t][j] = (short)f2bf(rem);
      }
    }
  }

  floatx4 o[8];
  #pragma unroll
  for (int dt = 0; dt < 8; ++dt) o[dt] = (floatx4){0.f, 0.f, 0.f, 0.f};
  float mrun[4], lrun[4];
  #pragma unroll
  for (int r = 0; r < 4; ++r) { mrun[r] = -1e30f; lrun[r] = 0.f; }

  for (int kt = 0; kt < M_ / KVBLK; ++kt) {
    const int kr0 = kt * KVBLK;
    __syncthreads();

    // ---- stage K tile as hi/lo bf16 + k2 (fp32) ----
    #pragma unroll
    for (int p = 0; p < (KVBLK * (D_ / 4)) / 256; ++p) {  // 8 passes
      int idx = p * 256 + tid;
      int row = idx >> 5;        // 0..63
      int c4  = idx & 31;        // float4 index within row
      float4 kq = *(const float4*)(kb + (size_t)(kr0 + row) * D_ + c4 * 4);
      float xs[4] = {kq.x, kq.y, kq.z, kq.w};
      u16 hh[4], ll[4];
      float ss = 0.f;
      #pragma unroll
      for (int j = 0; j < 4; ++j) {
        u16 h = f2bf(xs[j]);
        hh[j] = h;
        ll[j] = f2bf(xs[j] - bf2f(h));
        ss += xs[j] * xs[j];
      }
      uint2 hv, lv;
      hv.x = (u32)hh[0] | ((u32)hh[1] << 16);
      hv.y = (u32)hh[2] | ((u32)hh[3] << 16);
      lv.x = (u32)ll[0] | ((u32)ll[1] << 16);
      lv.y = (u32)ll[2] | ((u32)ll[3] << 16);
      *(uint2*)&Khi[row][c4 * 4] = hv;
      *(uint2*)&Klo[row][c4 * 4] = lv;
      // row-sum of squares across the 32 threads covering this row
      ss += __shfl_xor(ss, 16);
      ss += __shfl_xor(ss, 8);
      ss += __shfl_xor(ss, 4);
      ss += __shfl_xor(ss, 2);
      ss += __shfl_xor(ss, 1);
      if ((tid & 31) == 0) k2s[row] = ss;
    }

    // ---- stage V transposed: Vt[d][krow] ----
    #pragma unroll
    for (int p = 0; p < (KVBLK * D_) / 256; ++p) {  // 32 passes
      int idx = p * 256 + tid;
      int row = idx >> 7;        // 0..63
      int d   = idx & 127;
      Vt[d][row] = f2bf(vb[(size_t)(kr0 + row) * D_ + d]);
    }
    __syncthreads();

    // ---- QK^T: S = 2*(qh*kh + ql*kh + qh*kl) - k2 ----
    floatx4 accS[4];
    #pragma unroll
    for (int c = 0; c < 4; ++c) accS[c] = (floatx4){0.f, 0.f, 0.f, 0.f};
    #pragma unroll
    for (int t = 0; t < 4; ++t) {
      #pragma unroll
      for (int c = 0; c < 4; ++c) {
        short8 bh = *(const short8*)&Khi[c * 16 + l15][t * 32 + l16 * 8];
        short8 bl = *(const short8*)&Klo[c * 16 + l15][t * 32 + l16 * 8];
        accS[c] = __builtin_amdgcn_mfma_f32_16x16x32_bf16(qh[t], bh, accS[c], 0, 0, 0);
        accS[c] = __builtin_amdgcn_mfma_f32_16x16x32_bf16(ql[t], bh, accS[c], 0, 0, 0);
        accS[c] = __builtin_amdgcn_mfma_f32_16x16x32_bf16(qh[t], bl, accS[c], 0, 0, 0);
      }
    }

    // ---- online softmax ----
    float sv[4][4];
    #pragma unroll
    for (int c = 0; c < 4; ++c) {
      float k2v = k2s[c * 16 + l15];
      #pragma unroll
      for (int r = 0; r < 4; ++r) sv[c][r] = 2.f * accS[c][r] - k2v;
    }
    float mnew[4], scl[4];
    #pragma unroll
    for (int r = 0; r < 4; ++r) {
      float m0 = fmaxf(fmaxf(sv[0][r], sv[1][r]), fmaxf(sv[2][r], sv[3][r]));
      m0 = fmaxf(m0, __shfl_xor(m0, 1));
      m0 = fmaxf(m0, __shfl_xor(m0, 2));
      m0 = fmaxf(m0, __shfl_xor(m0, 4));
      m0 = fmaxf(m0, __shfl_xor(m0, 8));
      mnew[r] = fmaxf(mrun[r], m0);
      scl[r] = __expf(mrun[r] - mnew[r]);
      mrun[r] = mnew[r];
    }
    #pragma unroll
    for (int c = 0; c < 4; ++c) {
      #pragma unroll
      for (int r = 0; r < 4; ++r) {
        float p = __expf(sv[c][r] - mnew[r]);
        sv[c][r] = p;
        Plds[w][l16 * 4 + r][c * 16 + l15] = f2bf(p);
      }
    }
    #pragma unroll
    for (int r = 0; r < 4; ++r) {
      float rsv = sv[0][r] + sv[1][r] + sv[2][r] + sv[3][r];
      rsv += __shfl_xor(rsv, 1);
      rsv += __shfl_xor(rsv, 2);
      rsv += __shfl_xor(rsv, 4);
      rsv += __shfl_xor(rsv, 8);
      lrun[r] = lrun[r] * scl[r] + rsv;
      #pragma unroll
      for (int dt = 0; dt < 8; ++dt) o[dt][r] *= scl[r];
    }

    // ---- PV: O += P @ V ----
    asm volatile("s_waitcnt lgkmcnt(0)" ::: "memory");
    short8 pf0 = *(const short8*)&Plds[w][l15][l16 * 8];
    short8 pf1 = *(const short8*)&Plds[w][l15][32 + l16 * 8];
    #pragma unroll
    for (int dt = 0; dt < 8; ++dt) {
      short8 vf0 = *(const short8*)&Vt[dt * 16 + l15][l16 * 8];
      short8 vf1 = *(const short8*)&Vt[dt * 16 + l15][32 + l16 * 8];
      o[dt] = __builtin_amdgcn_mfma_f32_16x16x32_bf16(pf0, vf0, o[dt], 0, 0, 0);
      o[dt] = __builtin_amdgcn_mfma_f32_16x16x32_bf16(pf1, vf1, o[dt], 0, 0, 0);
    }
  }

  // ---- epilogue: O / l ----
  #pragma unroll
  for (int r = 0; r < 4; ++r) {
    float inv = 1.0f / lrun[r];
    float* op = ob + (size_t)(q0 + w * 16 + l16 * 4 + r) * D_ + l15;
    #pragma unroll
    for (int dt = 0; dt < 8; ++dt) op[dt * 16] = o[dt][r] * inv;
  }
}

extern "C" void kernel_launch(void* const* d_in, const int* in_sizes, int n_in,
                              void* d_out, int out_size, void* d_ws, size_t ws_size,
                              hipStream_t stream) {
  const float* q = (const float*)d_in[0];
  const float* k = (const float*)d_in[1];
  const float* v = (const float*)d_in[2];
  float* out = (float*)d_out;
  dim3 grid(N_ / QBLK, B_);
  rbf_attn_kernel<<<grid, 256, 0, stream>>>(q, k, v, out);
}

// Round 2
// 77.707 us; speedup vs baseline: 5.4695x; 5.4695x over previous
//
#include <hip/hip_runtime.h>
#include <hip/hip_bf16.h>

#define B_ 4
#define N_ 2048
#define M_ 2048
#define D_ 128
#define QBLK 128
#define NWAVE 8
#define NTHREADS 512
#define KVBLK 64
#define SPLIT_MAX 8

typedef __attribute__((ext_vector_type(8))) short short8;
typedef __attribute__((ext_vector_type(4))) float floatx4;
typedef unsigned short u16;
typedef unsigned int u32;

__device__ __forceinline__ u16 f2bf(float x) {
  u32 u = __builtin_bit_cast(u32, x);
  u32 r = (u + 0x7FFFu + ((u >> 16) & 1u)) >> 16;
  return (u16)r;
}
__device__ __forceinline__ float bf2f(u16 h) {
  u32 u = ((u32)h) << 16;
  return __builtin_bit_cast(float, u);
}

// Each block: one 128-row q-tile (8 waves x 16 rows), one KV split chunk.
// Writes partial (O, m, l) to workspace; reduce kernel merges splits.
__global__ __launch_bounds__(NTHREADS) void rbf_attn_kernel(
    const float* __restrict__ q, const float* __restrict__ k,
    const float* __restrict__ v, float* __restrict__ out,
    float* __restrict__ Opart, float* __restrict__ mpart,
    float* __restrict__ lpart, int nsplit, int tiles_per_split)
{
  __shared__ u16 Khi[KVBLK][136];
  __shared__ u16 Klo[KVBLK][136];
  __shared__ u16 Vt[D_][72];
  __shared__ u16 Plds[NWAVE][16][72];
  __shared__ float k2s[KVBLK];

  const int tid = threadIdx.x;
  const int w = tid >> 6;
  const int lane = tid & 63;
  const int l15 = lane & 15;
  const int l16 = lane >> 4;

  const int b = blockIdx.y;
  const int q0 = blockIdx.x * QBLK;
  const int sp = blockIdx.z;
  const int kt0 = sp * tiles_per_split;

  const float* qb = q + (size_t)b * N_ * D_;
  const float* kb = k + (size_t)b * M_ * D_;
  const float* vb = v + (size_t)b * M_ * D_;

  // ---- Load Q fragments (hi/lo bf16 split). Wave's rows: q0 + w*16 + l15
  short8 qh[4], ql[4];
  {
    const float* qp = qb + (size_t)(q0 + w * 16 + l15) * D_ + l16 * 8;
    #pragma unroll
    for (int t = 0; t < 4; ++t) {
      float4 a = *(const float4*)(qp + t * 32);
      float4 c = *(const float4*)(qp + t * 32 + 4);
      float xs[8] = {a.x, a.y, a.z, a.w, c.x, c.y, c.z, c.w};
      #pragma unroll
      for (int j = 0; j < 8; ++j) {
        u16 h = f2bf(xs[j]);
        float rem = xs[j] - bf2f(h);
        qh[t][j] = (short)h;
        ql[t][j] = (short)f2bf(rem);
      }
    }
  }

  floatx4 o[8];
  #pragma unroll
  for (int dt = 0; dt < 8; ++dt) o[dt] = (floatx4){0.f, 0.f, 0.f, 0.f};
  float mrun[4], lrun[4];
  #pragma unroll
  for (int r = 0; r < 4; ++r) { mrun[r] = -1e30f; lrun[r] = 0.f; }

  for (int kt = kt0; kt < kt0 + tiles_per_split; ++kt) {
    const int kr0 = kt * KVBLK;
    __syncthreads();

    // ---- stage K tile as hi/lo bf16 + k2 (fp32) ----
    #pragma unroll
    for (int p = 0; p < (KVBLK * (D_ / 4)) / NTHREADS; ++p) {  // 4 passes
      int idx = p * NTHREADS + tid;
      int row = idx >> 5;        // 0..63
      int c4  = idx & 31;        // float4 index within row
      float4 kq = *(const float4*)(kb + (size_t)(kr0 + row) * D_ + c4 * 4);
      float xs[4] = {kq.x, kq.y, kq.z, kq.w};
      u16 hh[4], ll[4];
      float ss = 0.f;
      #pragma unroll
      for (int j = 0; j < 4; ++j) {
        u16 h = f2bf(xs[j]);
        hh[j] = h;
        ll[j] = f2bf(xs[j] - bf2f(h));
        ss += xs[j] * xs[j];
      }
      uint2 hv, lv;
      hv.x = (u32)hh[0] | ((u32)hh[1] << 16);
      hv.y = (u32)hh[2] | ((u32)hh[3] << 16);
      lv.x = (u32)ll[0] | ((u32)ll[1] << 16);
      lv.y = (u32)ll[2] | ((u32)ll[3] << 16);
      *(uint2*)&Khi[row][c4 * 4] = hv;
      *(uint2*)&Klo[row][c4 * 4] = lv;
      // row-sum of squares across the 32 threads covering this row
      ss += __shfl_xor(ss, 16);
      ss += __shfl_xor(ss, 8);
      ss += __shfl_xor(ss, 4);
      ss += __shfl_xor(ss, 2);
      ss += __shfl_xor(ss, 1);
      if ((tid & 31) == 0) k2s[row] = ss;
    }

    // ---- stage V transposed: Vt[d][krow] (float4 loads, scattered u16 writes)
    #pragma unroll
    for (int p = 0; p < (KVBLK * (D_ / 4)) / NTHREADS; ++p) {  // 4 passes
      int idx = p * NTHREADS + tid;
      int row = idx >> 5;        // 0..63
      int c4  = idx & 31;
      float4 vv = *(const float4*)(vb + (size_t)(kr0 + row) * D_ + c4 * 4);
      Vt[c4 * 4 + 0][row] = f2bf(vv.x);
      Vt[c4 * 4 + 1][row] = f2bf(vv.y);
      Vt[c4 * 4 + 2][row] = f2bf(vv.z);
      Vt[c4 * 4 + 3][row] = f2bf(vv.w);
    }
    __syncthreads();

    // ---- QK^T: S = 2*(qh*kh + ql*kh + qh*kl) - k2 ----
    floatx4 accS[4];
    #pragma unroll
    for (int c = 0; c < 4; ++c) accS[c] = (floatx4){0.f, 0.f, 0.f, 0.f};
    #pragma unroll
    for (int t = 0; t < 4; ++t) {
      #pragma unroll
      for (int c = 0; c < 4; ++c) {
        short8 bh = *(const short8*)&Khi[c * 16 + l15][t * 32 + l16 * 8];
        short8 bl = *(const short8*)&Klo[c * 16 + l15][t * 32 + l16 * 8];
        accS[c] = __builtin_amdgcn_mfma_f32_16x16x32_bf16(qh[t], bh, accS[c], 0, 0, 0);
        accS[c] = __builtin_amdgcn_mfma_f32_16x16x32_bf16(ql[t], bh, accS[c], 0, 0, 0);
        accS[c] = __builtin_amdgcn_mfma_f32_16x16x32_bf16(qh[t], bl, accS[c], 0, 0, 0);
      }
    }

    // ---- online softmax ----
    float sv[4][4];
    #pragma unroll
    for (int c = 0; c < 4; ++c) {
      float k2v = k2s[c * 16 + l15];
      #pragma unroll
      for (int r = 0; r < 4; ++r) sv[c][r] = 2.f * accS[c][r] - k2v;
    }
    float mnew[4], scl[4];
    #pragma unroll
    for (int r = 0; r < 4; ++r) {
      float m0 = fmaxf(fmaxf(sv[0][r], sv[1][r]), fmaxf(sv[2][r], sv[3][r]));
      m0 = fmaxf(m0, __shfl_xor(m0, 1));
      m0 = fmaxf(m0, __shfl_xor(m0, 2));
      m0 = fmaxf(m0, __shfl_xor(m0, 4));
      m0 = fmaxf(m0, __shfl_xor(m0, 8));
      mnew[r] = fmaxf(mrun[r], m0);
      scl[r] = __expf(mrun[r] - mnew[r]);
      mrun[r] = mnew[r];
    }
    #pragma unroll
    for (int c = 0; c < 4; ++c) {
      #pragma unroll
      for (int r = 0; r < 4; ++r) {
        float p = __expf(sv[c][r] - mnew[r]);
        sv[c][r] = p;
        Plds[w][l16 * 4 + r][c * 16 + l15] = f2bf(p);
      }
    }
    #pragma unroll
    for (int r = 0; r < 4; ++r) {
      float rsv = sv[0][r] + sv[1][r] + sv[2][r] + sv[3][r];
      rsv += __shfl_xor(rsv, 1);
      rsv += __shfl_xor(rsv, 2);
      rsv += __shfl_xor(rsv, 4);
      rsv += __shfl_xor(rsv, 8);
      lrun[r] = lrun[r] * scl[r] + rsv;
      #pragma unroll
      for (int dt = 0; dt < 8; ++dt) o[dt][r] *= scl[r];
    }

    // ---- PV: O += P @ V ----
    short8 pf0 = *(const short8*)&Plds[w][l15][l16 * 8];
    short8 pf1 = *(const short8*)&Plds[w][l15][32 + l16 * 8];
    #pragma unroll
    for (int dt = 0; dt < 8; ++dt) {
      short8 vf0 = *(const short8*)&Vt[dt * 16 + l15][l16 * 8];
      short8 vf1 = *(const short8*)&Vt[dt * 16 + l15][32 + l16 * 8];
      o[dt] = __builtin_amdgcn_mfma_f32_16x16x32_bf16(pf0, vf0, o[dt], 0, 0, 0);
      o[dt] = __builtin_amdgcn_mfma_f32_16x16x32_bf16(pf1, vf1, o[dt], 0, 0, 0);
    }
  }

  // ---- epilogue ----
  if (nsplit == 1) {
    float* ob = out + (size_t)b * N_ * D_;
    #pragma unroll
    for (int r = 0; r < 4; ++r) {
      float inv = 1.0f / lrun[r];
      float* op = ob + (size_t)(q0 + w * 16 + l16 * 4 + r) * D_ + l15;
      #pragma unroll
      for (int dt = 0; dt < 8; ++dt) op[dt * 16] = o[dt][r] * inv;
    }
  } else {
    size_t rowbase = ((size_t)sp * B_ + b) * N_ + q0 + w * 16;
    #pragma unroll
    for (int r = 0; r < 4; ++r) {
      size_t row = rowbase + l16 * 4 + r;
      float* op = Opart + row * D_ + l15;
      #pragma unroll
      for (int dt = 0; dt < 8; ++dt) op[dt * 16] = o[dt][r];
      if (l15 == 0) {
        mpart[row] = mrun[r];
        lpart[row] = lrun[r];
      }
    }
  }
}

// Merge split partials: out = sum_s e^{m_s-m*} O_s / sum_s e^{m_s-m*} l_s
__global__ __launch_bounds__(256) void rbf_reduce_kernel(
    const float* __restrict__ Opart, const float* __restrict__ mpart,
    const float* __restrict__ lpart, float* __restrict__ out, int nsplit)
{
  const int rid = blockIdx.x * 2 + (threadIdx.x >> 7);  // row in [0, B*N)
  const int d = threadIdx.x & 127;
  const size_t stride = (size_t)B_ * N_;
  float mmax = -1e30f;
  for (int s = 0; s < nsplit; ++s)
    mmax = fmaxf(mmax, mpart[(size_t)s * stride + rid]);
  float acc = 0.f, lsum = 0.f;
  for (int s = 0; s < nsplit; ++s) {
    float wv = __expf(mpart[(size_t)s * stride + rid] - mmax);
    lsum += wv * lpart[(size_t)s * stride + rid];
    acc += wv * Opart[((size_t)s * stride + rid) * D_ + d];
  }
  out[(size_t)rid * D_ + d] = acc / lsum;
}

extern "C" void kernel_launch(void* const* d_in, const int* in_sizes, int n_in,
                              void* d_out, int out_size, void* d_ws, size_t ws_size,
                              hipStream_t stream) {
  const float* q = (const float*)d_in[0];
  const float* k = (const float*)d_in[1];
  const float* v = (const float*)d_in[2];
  float* out = (float*)d_out;

  const size_t perO = (size_t)B_ * N_ * D_ * sizeof(float);
  const size_t perML = (size_t)B_ * N_ * sizeof(float);
  int nsplit = SPLIT_MAX;
  while (nsplit > 1 && (size_t)nsplit * (perO + 2 * perML) > ws_size) nsplit >>= 1;

  float* Opart = (float*)d_ws;
  float* mpart = Opart + (size_t)nsplit * B_ * N_ * D_;
  float* lpart = mpart + (size_t)nsplit * B_ * N_;
  int tiles_per_split = (M_ / KVBLK) / nsplit;

  dim3 grid(N_ / QBLK, B_, nsplit);
  rbf_attn_kernel<<<grid, NTHREADS, 0, stream>>>(
      q, k, v, out, Opart, mpart, lpart, nsplit, tiles_per_split);
  if (nsplit > 1) {
    rbf_reduce_kernel<<<B_ * N_ / 2, 256, 0, stream>>>(
        Opart, mpart, lpart, out, nsplit);
  }
}

// Round 3
// 63.437 us; speedup vs baseline: 6.6998x; 1.2249x over previous
//
#include <hip/hip_runtime.h>
#include <hip/hip_bf16.h>

#define B_ 4
#define N_ 2048
#define M_ 2048
#define D_ 128
#define QBLK 128
#define NWAVE 8
#define NTHREADS 512
#define KVBLK 64
#define NTILES 32           // M_/KVBLK per batch
#define TILE_BYTES 16384    // 64*128*2
#define SPLIT_MAX 8

typedef __attribute__((ext_vector_type(8))) short short8;
typedef __attribute__((ext_vector_type(4))) float floatx4;
typedef unsigned short u16;
typedef unsigned int u32;

__device__ __forceinline__ u16 f2bf(float x) {  // RNE, used in prep
  u32 u = __builtin_bit_cast(u32, x);
  u32 r = (u + 0x7FFFu + ((u >> 16) & 1u)) >> 16;
  return (u16)r;
}
__device__ __forceinline__ float bf2f(u16 h) {
  u32 u = ((u32)h) << 16;
  return __builtin_bit_cast(float, u);
}

#define GLOAD16(src, dst)                                                     \
  __builtin_amdgcn_global_load_lds(                                           \
      (const __attribute__((address_space(1))) void*)(src),                   \
      (__attribute__((address_space(3))) void*)(dst), 16, 0, 0)

// ---------------- prep K: khi/klo = bf16 hi/lo split of 2*K, k2 = ||k||^2 ---
// Layout: per (b,tile): 64x128 u16 tile image, 16B chunks XOR-swizzled by row.
__global__ __launch_bounds__(256) void prep_k_kernel(
    const float* __restrict__ k, u16* __restrict__ khi_g,
    u16* __restrict__ klo_g, float* __restrict__ k2_g)
{
  int gid = blockIdx.x * 256 + threadIdx.x;   // B_*M_*16 threads
  int row_g = gid >> 4;                       // b*M_ + m
  int j = gid & 15;                           // 16B chunk (8 elems)
  const float* kp = k + (size_t)row_g * D_ + j * 8;
  float4 a = *(const float4*)kp;
  float4 c = *(const float4*)(kp + 4);
  float xs[8] = {a.x, a.y, a.z, a.w, c.x, c.y, c.z, c.w};
  short8 hi, lo;
  float ss = 0.f;
  #pragma unroll
  for (int e = 0; e < 8; ++e) {
    ss += xs[e] * xs[e];
    float x2 = 2.f * xs[e];
    u16 h = f2bf(x2);
    hi[e] = (short)h;
    lo[e] = (short)f2bf(x2 - bf2f(h));
  }
  ss += __shfl_xor(ss, 1);
  ss += __shfl_xor(ss, 2);
  ss += __shfl_xor(ss, 4);
  ss += __shfl_xor(ss, 8);
  if (j == 0) k2_g[row_g] = ss;
  int m = row_g & (M_ - 1);
  int b = row_g >> 11;
  int tile = m >> 6, r = m & 63;
  size_t base = ((size_t)b * NTILES + tile) * TILE_BYTES;
  u32 off = (u32)(r * 256 + j * 16) ^ ((u32)(r & 7) << 4);
  *(short8*)((char*)khi_g + base + off) = hi;
  *(short8*)((char*)klo_g + base + off) = lo;
}

// ---------------- prep V: transpose to [d][krow] bf16 tiles, swizzled -------
__global__ __launch_bounds__(256) void prep_v_kernel(
    const float* __restrict__ v, u16* __restrict__ vt_g)
{
  __shared__ u16 T[64][136];
  int blk = blockIdx.x;            // B_*NTILES blocks
  int b = blk >> 5, tile = blk & 31;
  const float* vp = v + ((size_t)b * M_ + tile * 64) * D_;
  int tid = threadIdx.x;
  #pragma unroll
  for (int p = 0; p < 8; ++p) {
    int idx = p * 256 + tid;
    int r = idx >> 5, c4 = idx & 31;
    float4 vv = *(const float4*)(vp + (size_t)r * D_ + c4 * 4);
    T[r][c4 * 4 + 0] = f2bf(vv.x);
    T[r][c4 * 4 + 1] = f2bf(vv.y);
    T[r][c4 * 4 + 2] = f2bf(vv.z);
    T[r][c4 * 4 + 3] = f2bf(vv.w);
  }
  __syncthreads();
  size_t base = ((size_t)b * NTILES + tile) * TILE_BYTES;
  #pragma unroll
  for (int p = 0; p < 4; ++p) {
    int idx = p * 256 + tid;
    int d = idx >> 3, rb = idx & 7;
    short8 s;
    #pragma unroll
    for (int i = 0; i < 8; ++i) s[i] = (short)T[rb * 8 + i][d];
    u32 off = (u32)(d * 128 + rb * 16) ^ ((u32)(d & 7) << 4);
    *(short8*)((char*)vt_g + base + off) = s;
  }
}

// ---------------- main attention kernel -------------------------------------
__global__ __launch_bounds__(NTHREADS, 4) void rbf_attn_kernel(
    const float* __restrict__ q, const u16* __restrict__ khi_g,
    const u16* __restrict__ klo_g, const u16* __restrict__ vt_g,
    const float* __restrict__ k2_g, float* __restrict__ out,
    float* __restrict__ Opart, float* __restrict__ mpart,
    float* __restrict__ lpart, int nsplit, int tiles_per_split)
{
  __shared__ __align__(16) u16 KhiL[64 * 128];
  __shared__ __align__(16) u16 KloL[64 * 128];
  __shared__ __align__(16) u16 VtL[128 * 64];
  __shared__ u16 Plds[NWAVE][16][72];

  const int tid = threadIdx.x;
  const int w = tid >> 6;
  const int lane = tid & 63;
  const int l15 = lane & 15;
  const int l16 = lane >> 4;
  const u32 swz = (u32)(l15 & 7) << 4;

  const int b = blockIdx.y;
  const int q0 = blockIdx.x * QBLK;
  const int sp = blockIdx.z;
  const int kt0 = sp * tiles_per_split;

  // ---- Q fragments (hi/lo bf16 split), rows q0 + w*16 + l15
  short8 qh[4], ql[4];
  {
    const float* qp = q + ((size_t)b * N_ + q0 + w * 16 + l15) * D_ + l16 * 8;
    #pragma unroll
    for (int t = 0; t < 4; ++t) {
      float4 a = *(const float4*)(qp + t * 32);
      float4 c = *(const float4*)(qp + t * 32 + 4);
      float xs[8] = {a.x, a.y, a.z, a.w, c.x, c.y, c.z, c.w};
      #pragma unroll
      for (int j = 0; j < 8; ++j) {
        u16 h = f2bf(xs[j]);
        qh[t][j] = (short)h;
        ql[t][j] = (short)f2bf(xs[j] - bf2f(h));
      }
    }
  }

  const char* khi_b = (const char*)khi_g + (size_t)b * NTILES * TILE_BYTES;
  const char* klo_b = (const char*)klo_g + (size_t)b * NTILES * TILE_BYTES;
  const char* vt_b = (const char*)vt_g + (size_t)b * NTILES * TILE_BYTES;
  const float* k2_b = k2_g + (size_t)b * M_;

  floatx4 o[8];
  #pragma unroll
  for (int dt = 0; dt < 8; ++dt) o[dt] = (floatx4){0.f, 0.f, 0.f, 0.f};
  float mrun[4], lrun[4];
  #pragma unroll
  for (int r = 0; r < 4; ++r) { mrun[r] = -1e30f; lrun[r] = 0.f; }

  const int so = w * 2048 + lane * 16;

  for (int kt = kt0; kt < kt0 + tiles_per_split; ++kt) {
    const int kr0 = kt * KVBLK;
    __syncthreads();  // previous tile's compute done before overwrite

    // ---- stage K(hi,lo) + Vt via direct global->LDS DMA (zero VALU) ----
    {
      const char* kh = khi_b + (size_t)kt * TILE_BYTES;
      const char* kl = klo_b + (size_t)kt * TILE_BYTES;
      const char* vt = vt_b + (size_t)kt * TILE_BYTES;
      char* dkh = (char*)KhiL + w * 2048;
      char* dkl = (char*)KloL + w * 2048;
      char* dvt = (char*)VtL + w * 2048;
      GLOAD16(kh + so, dkh);
      GLOAD16(kh + so + 1024, dkh + 1024);
      GLOAD16(kl + so, dkl);
      GLOAD16(kl + so + 1024, dkl + 1024);
      GLOAD16(vt + so, dvt);
      GLOAD16(vt + so + 1024, dvt + 1024);
    }
    float k2v[4];
    #pragma unroll
    for (int c = 0; c < 4; ++c) k2v[c] = k2_b[kr0 + c * 16 + l15];
    asm volatile("s_waitcnt vmcnt(0)" ::: "memory");
    __syncthreads();

    // ---- QK^T (K pre-scaled by 2): S = qh*Kh + ql*Kh + qh*Kl - k2 ----
    floatx4 accS[4];
    #pragma unroll
    for (int c = 0; c < 4; ++c) accS[c] = (floatx4){0.f, 0.f, 0.f, 0.f};
    #pragma unroll
    for (int t = 0; t < 4; ++t) {
      #pragma unroll
      for (int c = 0; c < 4; ++c) {
        u32 off = ((u32)((c * 16 + l15) * 256 + (t * 4 + l16) * 16)) ^ swz;
        short8 bh = *(const short8*)((const char*)KhiL + off);
        short8 bl = *(const short8*)((const char*)KloL + off);
        accS[c] = __builtin_amdgcn_mfma_f32_16x16x32_bf16(qh[t], bh, accS[c], 0, 0, 0);
        accS[c] = __builtin_amdgcn_mfma_f32_16x16x32_bf16(ql[t], bh, accS[c], 0, 0, 0);
        accS[c] = __builtin_amdgcn_mfma_f32_16x16x32_bf16(qh[t], bl, accS[c], 0, 0, 0);
      }
    }

    // ---- online softmax with deferred max (THR=8) ----
    float pmax[4];
    #pragma unroll
    for (int r = 0; r < 4; ++r) {
      float m0 = accS[0][r] - k2v[0];
      m0 = fmaxf(m0, accS[1][r] - k2v[1]);
      m0 = fmaxf(m0, accS[2][r] - k2v[2]);
      m0 = fmaxf(m0, accS[3][r] - k2v[3]);
      m0 = fmaxf(m0, __shfl_xor(m0, 1));
      m0 = fmaxf(m0, __shfl_xor(m0, 2));
      m0 = fmaxf(m0, __shfl_xor(m0, 4));
      m0 = fmaxf(m0, __shfl_xor(m0, 8));
      pmax[r] = m0;
    }
    float g = fmaxf(fmaxf(pmax[0] - mrun[0], pmax[1] - mrun[1]),
                    fmaxf(pmax[2] - mrun[2], pmax[3] - mrun[3]));
    if (!__all(g <= 8.f)) {
      #pragma unroll
      for (int r = 0; r < 4; ++r) {
        float mnew = fmaxf(mrun[r], pmax[r]);
        float scl = __expf(mrun[r] - mnew);
        mrun[r] = mnew;
        lrun[r] *= scl;
        #pragma unroll
        for (int dt = 0; dt < 8; ++dt) o[dt][r] *= scl;
      }
    }
    float rs[4] = {0.f, 0.f, 0.f, 0.f};
    #pragma unroll
    for (int c = 0; c < 4; ++c) {
      #pragma unroll
      for (int r = 0; r < 4; ++r) {
        float p = __expf(accS[c][r] - k2v[c] - mrun[r]);
        rs[r] += p;
        Plds[w][l16 * 4 + r][c * 16 + l15] = f2bf(p);
      }
    }
    #pragma unroll
    for (int r = 0; r < 4; ++r) {
      float t0 = rs[r];
      t0 += __shfl_xor(t0, 1);
      t0 += __shfl_xor(t0, 2);
      t0 += __shfl_xor(t0, 4);
      t0 += __shfl_xor(t0, 8);
      lrun[r] += t0;
    }

    // ---- PV: O += P @ V (Vt swizzled) ----
    short8 pf0 = *(const short8*)&Plds[w][l15][l16 * 8];
    short8 pf1 = *(const short8*)&Plds[w][l15][32 + l16 * 8];
    #pragma unroll
    for (int dt = 0; dt < 8; ++dt) {
      int d = dt * 16 + l15;
      u32 off0 = ((u32)(d * 128 + l16 * 16)) ^ swz;
      u32 off1 = ((u32)(d * 128 + 64 + l16 * 16)) ^ swz;
      short8 vf0 = *(const short8*)((const char*)VtL + off0);
      short8 vf1 = *(const short8*)((const char*)VtL + off1);
      o[dt] = __builtin_amdgcn_mfma_f32_16x16x32_bf16(pf0, vf0, o[dt], 0, 0, 0);
      o[dt] = __builtin_amdgcn_mfma_f32_16x16x32_bf16(pf1, vf1, o[dt], 0, 0, 0);
    }
  }

  // ---- epilogue ----
  if (nsplit == 1) {
    float* ob = out + (size_t)b * N_ * D_;
    #pragma unroll
    for (int r = 0; r < 4; ++r) {
      float inv = 1.0f / lrun[r];
      float* op = ob + (size_t)(q0 + w * 16 + l16 * 4 + r) * D_ + l15;
      #pragma unroll
      for (int dt = 0; dt < 8; ++dt) op[dt * 16] = o[dt][r] * inv;
    }
  } else {
    size_t rowbase = ((size_t)sp * B_ + b) * N_ + q0 + w * 16;
    #pragma unroll
    for (int r = 0; r < 4; ++r) {
      size_t row = rowbase + l16 * 4 + r;
      float* op = Opart + row * D_ + l15;
      #pragma unroll
      for (int dt = 0; dt < 8; ++dt) op[dt * 16] = o[dt][r];
      if (l15 == 0) {
        mpart[row] = mrun[r];
        lpart[row] = lrun[r];
      }
    }
  }
}

// ---------------- split merge ----------------------------------------------
__global__ __launch_bounds__(256) void rbf_reduce_kernel(
    const float* __restrict__ Opart, const float* __restrict__ mpart,
    const float* __restrict__ lpart, float* __restrict__ out, int nsplit)
{
  const int rid = blockIdx.x * 2 + (threadIdx.x >> 7);
  const int d = threadIdx.x & 127;
  const size_t stride = (size_t)B_ * N_;
  float mmax = -1e30f;
  for (int s = 0; s < nsplit; ++s)
    mmax = fmaxf(mmax, mpart[(size_t)s * stride + rid]);
  float acc = 0.f, lsum = 0.f;
  for (int s = 0; s < nsplit; ++s) {
    float wv = __expf(mpart[(size_t)s * stride + rid] - mmax);
    lsum += wv * lpart[(size_t)s * stride + rid];
    acc += wv * Opart[((size_t)s * stride + rid) * D_ + d];
  }
  out[(size_t)rid * D_ + d] = acc / lsum;
}

extern "C" void kernel_launch(void* const* d_in, const int* in_sizes, int n_in,
                              void* d_out, int out_size, void* d_ws, size_t ws_size,
                              hipStream_t stream) {
  const float* q = (const float*)d_in[0];
  const float* k = (const float*)d_in[1];
  const float* v = (const float*)d_in[2];
  float* out = (float*)d_out;

  const size_t tileBytesAll = (size_t)B_ * NTILES * TILE_BYTES;  // 2 MB each
  u16* khi_g = (u16*)d_ws;
  u16* klo_g = (u16*)((char*)d_ws + tileBytesAll);
  u16* vt_g  = (u16*)((char*)d_ws + 2 * tileBytesAll);
  float* k2_g = (float*)((char*)d_ws + 3 * tileBytesAll);
  const size_t prepBytes = 3 * tileBytesAll + (size_t)B_ * M_ * sizeof(float);

  const size_t perO = (size_t)B_ * N_ * D_ * sizeof(float);
  const size_t perML = 2 * (size_t)B_ * N_ * sizeof(float);
  int nsplit = SPLIT_MAX;
  while (nsplit > 1 && prepBytes + (size_t)nsplit * (perO + perML) > ws_size)
    nsplit >>= 1;

  float* Opart = (float*)((char*)d_ws + prepBytes);
  float* mpart = Opart + (size_t)nsplit * B_ * N_ * D_;
  float* lpart = mpart + (size_t)nsplit * B_ * N_;
  int tiles_per_split = NTILES / nsplit;

  prep_k_kernel<<<(B_ * M_ * 16) / 256, 256, 0, stream>>>(k, khi_g, klo_g, k2_g);
  prep_v_kernel<<<B_ * NTILES, 256, 0, stream>>>(v, vt_g);

  dim3 grid(N_ / QBLK, B_, nsplit);
  rbf_attn_kernel<<<grid, NTHREADS, 0, stream>>>(
      q, khi_g, klo_g, vt_g, k2_g, out, Opart, mpart, lpart, nsplit,
      tiles_per_split);
  if (nsplit > 1) {
    rbf_reduce_kernel<<<B_ * N_ / 2, 256, 0, stream>>>(
        Opart, mpart, lpart, out, nsplit);
  }
}